// Round 3
// 714.174 us; speedup vs baseline: 1.0297x; 1.0297x over previous
//
#include <hip/hip_runtime.h>
#include <math.h>

// B=32, T=1, EMBED=1024, NUM_HEADS=16, HEAD_DIM=64, FFN=4096, S=1500, SC=448

__device__ __forceinline__ float4 f4add(float4 a, float4 b) {
  float4 r; r.x=a.x+b.x; r.y=a.y+b.y; r.z=a.z+b.z; r.w=a.w+b.w; return r;
}
__device__ __forceinline__ float dot4(float4 a, float4 b) {
  return a.x*b.x + a.y*b.y + a.z*b.z + a.w*b.w;
}
// sum 4 K-slices of a partial buffer P[4][32][1024] at float4 index idx
__device__ __forceinline__ float4 sum4(const float4* __restrict__ P4, int idx) {
  float4 a = P4[idx];
  a = f4add(a, P4[8192  + idx]);
  a = f4add(a, P4[16384 + idx]);
  a = f4add(a, P4[24576 + idx]);
  return a;
}

// ---------------- LayerNorm: x[32][1024] -> h[32][1024] ----------------
__global__ __launch_bounds__(256) void ln_k(const float* __restrict__ xin,
    const float* __restrict__ g, const float* __restrict__ bb,
    float* __restrict__ hout)
{
  int i = blockIdx.x, t = threadIdx.x;
  int wv = t >> 6, ln = t & 63;
  const float4* x4 = (const float4*)xin;
  float4 v = x4[i*256 + t];
  float s  = v.x+v.y+v.z+v.w;
  float sq = v.x*v.x+v.y*v.y+v.z*v.z+v.w*v.w;
  #pragma unroll
  for (int m = 1; m < 64; m <<= 1) { s += __shfl_xor(s, m, 64); sq += __shfl_xor(sq, m, 64); }
  __shared__ float rs[4], rq[4];
  if (ln == 0) { rs[wv] = s; rq[wv] = sq; }
  __syncthreads();
  s  = rs[0]+rs[1]+rs[2]+rs[3];
  sq = rq[0]+rq[1]+rq[2]+rq[3];
  float mean = s * (1.0f/1024.0f);
  float var  = sq * (1.0f/1024.0f) - mean*mean;
  float inv  = rsqrtf(var + 1e-5f);
  float4 gv = ((const float4*)g)[t];
  float4 bv = ((const float4*)bb)[t];
  float4 o;
  o.x = (v.x-mean)*inv*gv.x + bv.x;
  o.y = (v.y-mean)*inv*gv.y + bv.y;
  o.z = (v.z-mean)*inv*gv.z + bv.z;
  o.w = (v.w-mean)*inv*gv.w + bv.w;
  ((float4*)hout)[i*256 + t] = o;
}

// ------------- GEMM: P[slice][i][o] = h[32][E] @ W[O][E]^T (K-sliced) -------------
// grid = (O/16)*SK blocks, 256 thr. Each wave handles 4 consecutive output cols.
__global__ __launch_bounds__(256) void gemm32(const float* __restrict__ h,
    const float* __restrict__ w, float* __restrict__ P, int O, int E, int SK)
{
  int slice = blockIdx.x % SK;
  int cb    = blockIdx.x / SK;
  int t  = threadIdx.x;
  int wv = t >> 6, ln = t & 63;
  int es = ln & 15, rq = ln >> 4;
  int obase = cb*16 + wv*4;
  int E4  = E >> 2;
  int KW4 = E4 / SK;             // float4 per slice (64 or 256)
  int nch = KW4 >> 6;            // chunks of 64 float4 (1 or 4)
  int e40 = slice * KW4;
  const float4* h4 = (const float4*)h;
  const float4* w4 = (const float4*)w;
  __shared__ float4 hsX[2048];   // 32 KB, swizzled [j4][r][rq*16+es]

  float acc[4][8];
  #pragma unroll
  for (int c = 0; c < 4; ++c)
    #pragma unroll
    for (int r = 0; r < 8; ++r) acc[c][r] = 0.f;

  for (int ch = 0; ch < nch; ++ch) {
    __syncthreads();
    #pragma unroll
    for (int r8 = 0; r8 < 8; ++r8) {
      int f  = (r8 << 8) + t;        // 0..2047 flat float4 index in chunk
      int i  = f >> 6, e4 = f & 63;
      float4 vv = h4[i*E4 + e40 + (ch<<6) + e4];
      hsX[((f&3)<<9) + ((i&7)<<6) + ((i>>3)<<4) + (e4>>2)] = vv;
    }
    float4 wf[4][4];
    #pragma unroll
    for (int c = 0; c < 4; ++c)
      #pragma unroll
      for (int j = 0; j < 4; ++j)
        wf[c][j] = w4[(obase+c)*E4 + e40 + (ch<<6) + (es<<2) + j];
    __syncthreads();
    #pragma unroll
    for (int j4 = 0; j4 < 4; ++j4)
      #pragma unroll
      for (int r = 0; r < 8; ++r) {
        float4 hv = hsX[(j4<<9) + (r<<6) + ln];
        #pragma unroll
        for (int c = 0; c < 4; ++c)
          acc[c][r] = fmaf(wf[c][j4].x, hv.x,
                      fmaf(wf[c][j4].y, hv.y,
                      fmaf(wf[c][j4].z, hv.z,
                      fmaf(wf[c][j4].w, hv.w, acc[c][r]))));
      }
  }
  #pragma unroll
  for (int c = 0; c < 4; ++c)
    #pragma unroll
    for (int r = 0; r < 8; ++r) {
      float v = acc[c][r];
      v += __shfl_xor(v, 1, 16);
      v += __shfl_xor(v, 2, 16);
      v += __shfl_xor(v, 4, 16);
      v += __shfl_xor(v, 8, 16);
      acc[c][r] = v;
    }
  if (es < 4) {
    int c = es;
    #pragma unroll
    for (int r = 0; r < 8; ++r)
      P[slice*32*O + (rq*8 + r)*O + obase + c] = acc[c][r];
  }
}

// ------------- fused self-attention + KV-cache writeback -------------
// grid 512 = b*16+h ; lane = (sg = s-subrow 0..3, c4 = float4 col 0..15)
// Loops split into unguarded main (unrolled for MLP) + guarded tail.
__global__ __launch_bounds__(256) void self_attn_k(
    const float* __restrict__ Pq, const float* __restrict__ Pk, const float* __restrict__ Pv,
    const float* __restrict__ qb, const float* __restrict__ kb, const float* __restrict__ vb,
    const float* __restrict__ kin, const float* __restrict__ vin,
    const float* __restrict__ mask,
    float* __restrict__ kout, float* __restrict__ vout,
    float* __restrict__ aout)
{
  int blk = blockIdx.x; int b = blk >> 4, h = blk & 15;
  int t = threadIdx.x, wv = t >> 6, ln = t & 63;
  int c4 = ln & 15, sg = ln >> 4;
  __shared__ float sc[448];
  __shared__ float wred[8];
  __shared__ float4 wo[4][16];

  int hq4 = b*256 + h*16 + c4;   // float4 index into [32][1024]
  const float4* Pq4 = (const float4*)Pq;
  const float4* Pk4 = (const float4*)Pk;
  const float4* Pv4 = (const float4*)Pv;
  float4 qv = sum4(Pq4, hq4);
  float4 qbv = ((const float4*)qb)[h*16 + c4];
  qv.x = (qv.x + qbv.x)*0.125f; qv.y = (qv.y + qbv.y)*0.125f;
  qv.z = (qv.z + qbv.z)*0.125f; qv.w = (qv.w + qbv.w)*0.125f;
  float4 kbv = ((const float4*)kb)[h*16 + c4];
  float4 vbv = ((const float4*)vb)[h*16 + c4];

  const float4* kin4 = (const float4*)kin;
  const float4* vin4 = (const float4*)vin;
  float4* kout4 = (float4*)kout;
  float4* vout4 = (float4*)vout;
  size_t cbase = (size_t)b*448*256 + h*16 + c4;

  // ---- K pass: scores + cache writeback (main: s <= 431, all-copy) ----
  #pragma unroll 9
  for (int it = 0; it < 27; ++it) {
    int s = it*16 + wv*4 + sg;
    float4 kv = kin4[cbase + (size_t)s*256];
    kout4[cbase + (size_t)s*256] = kv;
    float p = dot4(qv, kv);
    p += __shfl_xor(p, 1, 16);
    p += __shfl_xor(p, 2, 16);
    p += __shfl_xor(p, 4, 16);
    p += __shfl_xor(p, 8, 16);
    if (c4 == 0) sc[s] = p + mask[s];
  }
  { // tail it=27: s in 432..447, contains the computed row 447
    int s = 432 + wv*4 + sg;
    float4 kv;
    if (s < 447) kv = kin4[cbase + (size_t)s*256];
    else { kv = sum4(Pk4, hq4); kv = f4add(kv, kbv); }
    kout4[cbase + (size_t)s*256] = kv;
    float p = dot4(qv, kv);
    p += __shfl_xor(p, 1, 16);
    p += __shfl_xor(p, 2, 16);
    p += __shfl_xor(p, 4, 16);
    p += __shfl_xor(p, 8, 16);
    if (c4 == 0) sc[s] = p + mask[s];
  }
  __syncthreads();
  // ---- softmax ----
  float mx = -1e30f;
  for (int s = t; s < 448; s += 256) mx = fmaxf(mx, sc[s]);
  #pragma unroll
  for (int m = 1; m < 64; m <<= 1) mx = fmaxf(mx, __shfl_xor(mx, m, 64));
  if (ln == 0) wred[wv] = mx;
  __syncthreads();
  mx = fmaxf(fmaxf(wred[0], wred[1]), fmaxf(wred[2], wred[3]));
  float ss = 0.f;
  for (int s = t; s < 448; s += 256) { float e = __expf(sc[s]-mx); sc[s] = e; ss += e; }
  #pragma unroll
  for (int m = 1; m < 64; m <<= 1) ss += __shfl_xor(ss, m, 64);
  if (ln == 0) wred[4 + wv] = ss;
  __syncthreads();
  float inv = 1.0f / (wred[4]+wred[5]+wred[6]+wred[7]);
  // ---- V pass: weighted sum + cache writeback ----
  float4 acc; acc.x = acc.y = acc.z = acc.w = 0.f;
  #pragma unroll 9
  for (int it = 0; it < 27; ++it) {
    int s = it*16 + wv*4 + sg;
    float4 vv = vin4[cbase + (size_t)s*256];
    vout4[cbase + (size_t)s*256] = vv;
    float pw = sc[s];
    acc.x = fmaf(pw, vv.x, acc.x); acc.y = fmaf(pw, vv.y, acc.y);
    acc.z = fmaf(pw, vv.z, acc.z); acc.w = fmaf(pw, vv.w, acc.w);
  }
  { // tail it=27
    int s = 432 + wv*4 + sg;
    float4 vv;
    if (s < 447) vv = vin4[cbase + (size_t)s*256];
    else { vv = sum4(Pv4, hq4); vv = f4add(vv, vbv); }
    vout4[cbase + (size_t)s*256] = vv;
    float pw = sc[s];
    acc.x = fmaf(pw, vv.x, acc.x); acc.y = fmaf(pw, vv.y, acc.y);
    acc.z = fmaf(pw, vv.z, acc.z); acc.w = fmaf(pw, vv.w, acc.w);
  }
  acc.x += __shfl_xor(acc.x, 16, 64); acc.x += __shfl_xor(acc.x, 32, 64);
  acc.y += __shfl_xor(acc.y, 16, 64); acc.y += __shfl_xor(acc.y, 32, 64);
  acc.z += __shfl_xor(acc.z, 16, 64); acc.z += __shfl_xor(acc.z, 32, 64);
  acc.w += __shfl_xor(acc.w, 16, 64); acc.w += __shfl_xor(acc.w, 32, 64);
  if (sg == 0) wo[wv][c4] = acc;
  __syncthreads();
  if (t < 64) {
    const float* wof = (const float*)wo;
    float v = wof[t] + wof[64+t] + wof[128+t] + wof[192+t];
    aout[b*1024 + h*64 + t] = v * inv;
  }
}

// ------------- cross-attention (S=1500, pre-projected K/V, no mask) -------------
// Loops split into unguarded main (unrolled for MLP) + guarded tail.
__global__ __launch_bounds__(256) void cross_attn_k(
    const float* __restrict__ Pq, const float* __restrict__ qb,
    const float* __restrict__ kin, const float* __restrict__ vin,
    float* __restrict__ aout)
{
  int blk = blockIdx.x; int b = blk >> 4, h = blk & 15;
  int t = threadIdx.x, wv = t >> 6, ln = t & 63;
  int c4 = ln & 15, sg = ln >> 4;
  __shared__ float sc[1500];
  __shared__ float wred[8];
  __shared__ float4 wo[4][16];

  int hq4 = b*256 + h*16 + c4;
  float4 qv = sum4((const float4*)Pq, hq4);
  float4 qbv = ((const float4*)qb)[h*16 + c4];
  qv.x = (qv.x + qbv.x)*0.125f; qv.y = (qv.y + qbv.y)*0.125f;
  qv.z = (qv.z + qbv.z)*0.125f; qv.w = (qv.w + qbv.w)*0.125f;

  const float4* kin4 = (const float4*)kin;
  const float4* vin4 = (const float4*)vin;
  size_t cbase = (size_t)b*1500*256 + h*16 + c4;

  // ---- K pass: main 93 iterations unguarded (s <= 1487), tail guarded ----
  #pragma unroll 8
  for (int it = 0; it < 93; ++it) {
    int s = it*16 + wv*4 + sg;
    float4 kv = kin4[cbase + (size_t)s*256];
    float p = dot4(qv, kv);
    p += __shfl_xor(p, 1, 16);
    p += __shfl_xor(p, 2, 16);
    p += __shfl_xor(p, 4, 16);
    p += __shfl_xor(p, 8, 16);
    if (c4 == 0) sc[s] = p;
  }
  { // tail it=93: s in 1488..1503, guard < 1500
    int s = 1488 + wv*4 + sg;
    if (s < 1500) {
      float4 kv = kin4[cbase + (size_t)s*256];
      float p = dot4(qv, kv);
      p += __shfl_xor(p, 1, 16);
      p += __shfl_xor(p, 2, 16);
      p += __shfl_xor(p, 4, 16);
      p += __shfl_xor(p, 8, 16);
      if (c4 == 0) sc[s] = p;
    }
  }
  __syncthreads();
  float mx = -1e30f;
  for (int s = t; s < 1500; s += 256) mx = fmaxf(mx, sc[s]);
  #pragma unroll
  for (int m = 1; m < 64; m <<= 1) mx = fmaxf(mx, __shfl_xor(mx, m, 64));
  if (ln == 0) wred[wv] = mx;
  __syncthreads();
  mx = fmaxf(fmaxf(wred[0], wred[1]), fmaxf(wred[2], wred[3]));
  float ss = 0.f;
  for (int s = t; s < 1500; s += 256) { float e = __expf(sc[s]-mx); sc[s] = e; ss += e; }
  #pragma unroll
  for (int m = 1; m < 64; m <<= 1) ss += __shfl_xor(ss, m, 64);
  if (ln == 0) wred[4 + wv] = ss;
  __syncthreads();
  float inv = 1.0f / (wred[4]+wred[5]+wred[6]+wred[7]);
  // ---- V pass: main 93 unguarded + tail ----
  float4 acc; acc.x = acc.y = acc.z = acc.w = 0.f;
  #pragma unroll 8
  for (int it = 0; it < 93; ++it) {
    int s = it*16 + wv*4 + sg;
    float4 vv = vin4[cbase + (size_t)s*256];
    float pw = sc[s];
    acc.x = fmaf(pw, vv.x, acc.x); acc.y = fmaf(pw, vv.y, acc.y);
    acc.z = fmaf(pw, vv.z, acc.z); acc.w = fmaf(pw, vv.w, acc.w);
  }
  { // tail
    int s = 1488 + wv*4 + sg;
    if (s < 1500) {
      float4 vv = vin4[cbase + (size_t)s*256];
      float pw = sc[s];
      acc.x = fmaf(pw, vv.x, acc.x); acc.y = fmaf(pw, vv.y, acc.y);
      acc.z = fmaf(pw, vv.z, acc.z); acc.w = fmaf(pw, vv.w, acc.w);
    }
  }
  acc.x += __shfl_xor(acc.x, 16, 64); acc.x += __shfl_xor(acc.x, 32, 64);
  acc.y += __shfl_xor(acc.y, 16, 64); acc.y += __shfl_xor(acc.y, 32, 64);
  acc.z += __shfl_xor(acc.z, 16, 64); acc.z += __shfl_xor(acc.z, 32, 64);
  acc.w += __shfl_xor(acc.w, 16, 64); acc.w += __shfl_xor(acc.w, 32, 64);
  if (sg == 0) wo[wv][c4] = acc;
  __syncthreads();
  if (t < 64) {
    const float* wof = (const float*)wo;
    float v = wof[t] + wof[64+t] + wof[128+t] + wof[192+t];
    aout[b*1024 + h*64 + t] = v * inv;
  }
}

// ------------- epilogue: x = res + sum(P) + bias ; h = LN(x) -------------
__global__ __launch_bounds__(256) void ep_res_ln(
    const float* __restrict__ P, const float* __restrict__ bias,
    const float* __restrict__ res,
    const float* __restrict__ g, const float* __restrict__ bb,
    float* __restrict__ xout, float* __restrict__ hout)
{
  int i = blockIdx.x, t = threadIdx.x;
  int wv = t >> 6, ln = t & 63;
  float4 a = sum4((const float4*)P, i*256 + t);
  float4 bv4 = ((const float4*)bias)[t];
  float4 rv  = ((const float4*)res)[i*256 + t];
  float4 v;
  v.x = rv.x + a.x + bv4.x; v.y = rv.y + a.y + bv4.y;
  v.z = rv.z + a.z + bv4.z; v.w = rv.w + a.w + bv4.w;
  ((float4*)xout)[i*256 + t] = v;
  float s  = v.x+v.y+v.z+v.w;
  float sq = v.x*v.x+v.y*v.y+v.z*v.z+v.w*v.w;
  #pragma unroll
  for (int m = 1; m < 64; m <<= 1) { s += __shfl_xor(s, m, 64); sq += __shfl_xor(sq, m, 64); }
  __shared__ float rs[4], rq[4];
  if (ln == 0) { rs[wv] = s; rq[wv] = sq; }
  __syncthreads();
  s  = rs[0]+rs[1]+rs[2]+rs[3];
  sq = rq[0]+rq[1]+rq[2]+rq[3];
  float mean = s * (1.0f/1024.0f);
  float var  = sq * (1.0f/1024.0f) - mean*mean;
  float inv  = rsqrtf(var + 1e-5f);
  float4 gv = ((const float4*)g)[t];
  float4 lb = ((const float4*)bb)[t];
  float4 o;
  o.x = (v.x-mean)*inv*gv.x + lb.x;
  o.y = (v.y-mean)*inv*gv.y + lb.y;
  o.z = (v.z-mean)*inv*gv.z + lb.z;
  o.w = (v.w-mean)*inv*gv.w + lb.w;
  ((float4*)hout)[i*256 + t] = o;
}

// ------------- epilogue: mid = gelu(P + bias), P is [1][32][4096] -------------
__global__ __launch_bounds__(256) void ep_gelu(
    const float* __restrict__ P, const float* __restrict__ bias, float* __restrict__ mid)
{
  int i = blockIdx.x, t = threadIdx.x;
  const float4* P4 = (const float4*)P;
  const float4* b4 = (const float4*)bias;
  float4* m4 = (float4*)mid;
  #pragma unroll
  for (int j = 0; j < 4; ++j) {
    int o4 = (j << 8) + t;
    float4 v = P4[i*1024 + o4];
    float4 bv = b4[o4];
    v.x += bv.x; v.y += bv.y; v.z += bv.z; v.w += bv.w;
    float4 r;
    r.x = 0.5f*v.x*(1.0f + erff(v.x*0.70710678f));
    r.y = 0.5f*v.y*(1.0f + erff(v.y*0.70710678f));
    r.z = 0.5f*v.z*(1.0f + erff(v.z*0.70710678f));
    r.w = 0.5f*v.w*(1.0f + erff(v.w*0.70710678f));
    m4[i*1024 + o4] = r;
  }
}

// ------------- epilogue: out = res + sum(P) + bias -------------
__global__ __launch_bounds__(256) void ep_final(
    const float* __restrict__ P, const float* __restrict__ bias,
    const float* __restrict__ res, float* __restrict__ outx)
{
  int i = blockIdx.x, t = threadIdx.x;
  float4 a = sum4((const float4*)P, i*256 + t);
  float4 bv = ((const float4*)bias)[t];
  float4 rv = ((const float4*)res)[i*256 + t];
  float4 v;
  v.x = rv.x + a.x + bv.x; v.y = rv.y + a.y + bv.y;
  v.z = rv.z + a.z + bv.z; v.w = rv.w + a.w + bv.w;
  ((float4*)outx)[i*256 + t] = v;
}

extern "C" void kernel_launch(void* const* d_in, const int* in_sizes, int n_in,
                              void* d_out, int out_size, void* d_ws, size_t ws_size,
                              hipStream_t stream) {
  const float* x    = (const float*)d_in[0];
  const float* kci  = (const float*)d_in[1];
  const float* vci  = (const float*)d_in[2];
  const float* ck   = (const float*)d_in[3];
  const float* cv   = (const float*)d_in[4];
  const float* mask = (const float*)d_in[5];
  const float* ln1g = (const float*)d_in[6];  const float* ln1b = (const float*)d_in[7];
  const float* qw = (const float*)d_in[8];    const float* qb = (const float*)d_in[9];
  const float* kw = (const float*)d_in[10];   const float* kb = (const float*)d_in[11];
  const float* vw = (const float*)d_in[12];   const float* vb = (const float*)d_in[13];
  const float* ow = (const float*)d_in[14];   const float* ob = (const float*)d_in[15];
  const float* ln2g = (const float*)d_in[16]; const float* ln2b = (const float*)d_in[17];
  const float* caqw = (const float*)d_in[18]; const float* caqb = (const float*)d_in[19];
  const float* caow = (const float*)d_in[20]; const float* caob = (const float*)d_in[21];
  const float* ln3g = (const float*)d_in[22]; const float* ln3b = (const float*)d_in[23];
  const float* f1w = (const float*)d_in[24];  const float* f1b = (const float*)d_in[25];
  const float* f2w = (const float*)d_in[26];  const float* f2b = (const float*)d_in[27];

  float* outx = (float*)d_out;
  float* outk = outx + 32768;
  float* outv = outk + 14680064;

  float* W = (float*)d_ws;
  float* h1    = W;
  float* attn1 = W + 32768;
  float* x1    = W + 65536;
  float* h2    = W + 98304;
  float* attn2 = W + 131072;
  float* x2    = W + 163840;
  float* h3    = W + 196608;
  float* mid   = W + 229376;   // 32*4096
  float* PA    = W + 360448;   // 4*32*1024 (or 1*32*4096)
  float* PB    = W + 491520;
  float* PC    = W + 622592;

  // ---- self-attention block ----
  ln_k<<<32, 256, 0, stream>>>(x, ln1g, ln1b, h1);
  gemm32<<<256, 256, 0, stream>>>(h1, qw, PA, 1024, 1024, 4);
  gemm32<<<256, 256, 0, stream>>>(h1, kw, PB, 1024, 1024, 4);
  gemm32<<<256, 256, 0, stream>>>(h1, vw, PC, 1024, 1024, 4);
  self_attn_k<<<512, 256, 0, stream>>>(PA, PB, PC, qb, kb, vb, kci, vci, mask,
                                       outk, outv, attn1);
  gemm32<<<256, 256, 0, stream>>>(attn1, ow, PA, 1024, 1024, 4);
  ep_res_ln<<<32, 256, 0, stream>>>(PA, ob, x, ln2g, ln2b, x1, h2);
  // ---- cross-attention block ----
  gemm32<<<256, 256, 0, stream>>>(h2, caqw, PA, 1024, 1024, 4);
  cross_attn_k<<<512, 256, 0, stream>>>(PA, caqb, ck, cv, attn2);
  gemm32<<<256, 256, 0, stream>>>(attn2, caow, PA, 1024, 1024, 4);
  ep_res_ln<<<32, 256, 0, stream>>>(PA, caob, x1, ln3g, ln3b, x2, h3);
  // ---- FFN ----
  gemm32<<<256, 256, 0, stream>>>(h3, f1w, PA, 4096, 1024, 1);
  ep_gelu<<<32, 256, 0, stream>>>(PA, f1b, mid);
  gemm32<<<256, 256, 0, stream>>>(mid, f2w, PB, 1024, 4096, 4);
  ep_final<<<32, 256, 0, stream>>>(PB, f2b, x2, outx);
}